// Round 5
// baseline (488.010 us; speedup 1.0000x reference)
//
#include <hip/hip_runtime.h>

// AbstractLinear: y = x @ W.T + b  (256x8192x8192, bf16 MFMA)
//                 IBP bounds: P = W@(l+h), R = |W|@(h-l);
//                 low=.5(P-R)+b, high=.5(P+R)+b
// R5: (1) TM=32/TN=64 -> 1024 blocks = 4 blocks/CU = 4 waves/SIMD (occupancy
//     is the only lever that has moved R1-R4). (2) dispatch swizzle: the 8
//     blocks sharing a W tile are 8 apart (same XCD, time-adjacent) so L2
//     absorbs W reuse (R4 FETCH blew up 2x from K-phase drift). (3) bounds
//     K-split: every block accumulates P,R for tile>>4==m_tile only (pace
//     symmetry -> no drift), partials to d_ws, tiny combine kernel finishes.
#define M_TOTAL 256
#define N_TOTAL 8192
#define K_TOTAL 8192
#define TM 32
#define TN 64
#define BK 64
#define KITERS (K_TOTAL / BK)   // 128
#define MT 8                    // M tiles

typedef __attribute__((ext_vector_type(4))) float f32x4;
typedef __attribute__((ext_vector_type(8))) short s16x8;
typedef __attribute__((ext_vector_type(2))) int i32x2;

// pack two fp32 -> two bf16 (truncation) in one v_perm_b32
__device__ __forceinline__ int pk(float a, float b) {
    return (int)__builtin_amdgcn_perm(__float_as_uint(b), __float_as_uint(a), 0x07060302u);
}

// barrier with LDS-visibility only: does NOT drain vmcnt, so global
// prefetch loads issued before it remain in flight.
__device__ __forceinline__ void barrier_lds() {
    asm volatile("s_waitcnt lgkmcnt(0)\n\ts_barrier" ::: "memory");
}

__global__ __launch_bounds__(256, 4)
void abstract_linear_kernel(const float* __restrict__ x,
                            const float* __restrict__ low,
                            const float* __restrict__ high,
                            const float* __restrict__ W,
                            const float* __restrict__ bias,
                            float* __restrict__ out,
                            float* __restrict__ Pp,
                            float* __restrict__ Rp,
                            int split) {
    // XOR-swizzled bf16 tiles: element (row,k) at row*BK + ((k/8)^(row&7))*8 + k%8
    __shared__ __align__(16) unsigned short As[2][TM * BK];   // 2 x 4 KB
    __shared__ __align__(16) unsigned short Bs[2][TN * BK];   // 2 x 8 KB

    const int t  = threadIdx.x;
    const int bx = blockIdx.x;
    // swizzle: same-n_tile blocks are {+8,+16,..} apart -> same XCD (bx%8
    // preserved), dispatched within one 64-block window.
    const int m_tile = (bx >> 3) & 7;
    const int n_tile = (bx & 7) | ((bx >> 6) << 3);
    const int m0 = m_tile * TM;
    const int n0 = n_tile * TN;

    // coalesced staging map: thread t -> rows j*16 + g, cols sg*4..sg*4+3
    const int g  = t >> 4;            // 0..15
    const int sg = t & 15;            // 0..15

    const float* xg = x + (size_t)(m0 + g) * K_TOTAL + sg * 4;
    const float* wg = W + (size_t)(n0 + g) * K_TOTAL + sg * 4;
    const float* lg = low  + sg * 4;
    const float* hg = high + sg * 4;

    // wave / fragment mapping: 4 waves side by side in N, wave tile 32x16
    const int wave = t >> 6;
    const int lane = t & 63;
    const int l15 = lane & 15;
    const int lq  = lane >> 4;

    f32x4 acc[2];
    acc[0] = (f32x4){0.f, 0.f, 0.f, 0.f};
    acc[1] = (f32x4){0.f, 0.f, 0.f, 0.f};

    // bounds accumulators: P[j]/R[j] for W row j*16+g, this thread's 4 cols
    float P[4] = {0.f, 0.f, 0.f, 0.f};
    float R[4] = {0.f, 0.f, 0.f, 0.f};

    // which K-tiles this block accumulates bounds for (pace-symmetric split:
    // 16 of 128 tiles each; fallback: m_tile 0 does all)
    auto acc_gate = [&](int tile) -> bool {
        return split ? ((tile >> 4) == m_tile) : (m_tile == 0);
    };

    // 2-slot register pipeline
    f32x4 a_reg[2][2], w_reg[2][4], lo_reg[2], hi_reg[2];

    auto issue = [&](int sl, int tile) {
        const int kb = tile * BK;
#pragma unroll
        for (int j = 0; j < 2; ++j)
            a_reg[sl][j] = *(const f32x4*)(xg + (size_t)j * 16 * K_TOTAL + kb);
#pragma unroll
        for (int j = 0; j < 4; ++j)
            w_reg[sl][j] = *(const f32x4*)(wg + (size_t)j * 16 * K_TOTAL + kb);
        if (acc_gate(tile)) {
            lo_reg[sl] = *(const f32x4*)(lg + kb);
            hi_reg[sl] = *(const f32x4*)(hg + kb);
        }
    };

    const int a_chunk = sg >> 1;      // 16B chunk within row
    const int a_half  = sg & 1;       // 8B half within chunk

    auto convert_write = [&](int sl, int buf, int tile) {
#pragma unroll
        for (int j = 0; j < 2; ++j) {
            f32x4 u = a_reg[sl][j];
            i32x2 d;
            d[0] = pk(u[0], u[1]);
            d[1] = pk(u[2], u[3]);
            int row = j * 16 + g;
            int pos = a_chunk ^ (row & 7);
            *(i32x2*)&As[buf][row * BK + pos * 8 + a_half * 4] = d;
        }
#pragma unroll
        for (int j = 0; j < 4; ++j) {
            f32x4 u = w_reg[sl][j];
            i32x2 d;
            d[0] = pk(u[0], u[1]);
            d[1] = pk(u[2], u[3]);
            int row = j * 16 + g;
            int pos = a_chunk ^ (row & 7);
            *(i32x2*)&Bs[buf][row * BK + pos * 8 + a_half * 4] = d;
        }
        if (acc_gate(tile)) {
            f32x4 l = lo_reg[sl], h = hi_reg[sl];
#pragma unroll
            for (int j = 0; j < 4; ++j) {
                f32x4 w = w_reg[sl][j];
#pragma unroll
                for (int e = 0; e < 4; ++e) {
                    float wv = w[e];
                    P[j] = fmaf(wv,        l[e] + h[e], P[j]);
                    R[j] = fmaf(fabsf(wv), h[e] - l[e], R[j]);
                }
            }
        }
    };

    auto mfma_tile = [&](int buf) {
#pragma unroll
        for (int s = 0; s < 2; ++s) {
            s16x8 af[2], bf;
#pragma unroll
            for (int mi = 0; mi < 2; ++mi) {
                int row = mi * 16 + l15;
                int pos = (s * 4 + lq) ^ (row & 7);
                af[mi] = *(const s16x8*)&As[buf][row * BK + pos * 8];
            }
            {
                int row = wave * 16 + l15;
                int pos = (s * 4 + lq) ^ (row & 7);
                bf = *(const s16x8*)&Bs[buf][row * BK + pos * 8];
            }
#pragma unroll
            for (int mi = 0; mi < 2; ++mi)
                acc[mi] = __builtin_amdgcn_mfma_f32_16x16x32_bf16(
                    af[mi], bf, acc[mi], 0, 0, 0);
        }
    };

    // ---- prologue: tiles 0,1 in flight; tile 0 staged to LDS buf 0 ----
    issue(0, 0);
    issue(1, 1);
    convert_write(0, 0, 0);
    barrier_lds();

    // ---- main pipeline, unrolled x2 (slot/buf indices literal) ----
    for (int it = 0; it < KITERS - 2; it += 2) {
        issue(0, it + 2);
        mfma_tile(0);
        convert_write(1, 1, it + 1);
        barrier_lds();

        issue(1, it + 3);
        mfma_tile(1);
        convert_write(0, 0, it + 2);
        barrier_lds();
    }
    // tail: tiles 126, 127
    mfma_tile(0);
    convert_write(1, 1, KITERS - 1);
    barrier_lds();
    mfma_tile(1);

    // ---- epilogue: y = acc + b  (C/D layout: col = lane&15, row = lq*4+reg) ----
    {
        int go = n0 + wave * 16 + l15;
        float bv = bias[go];
#pragma unroll
        for (int mi = 0; mi < 2; ++mi) {
            int gr = m0 + mi * 16 + lq * 4;
#pragma unroll
            for (int r = 0; r < 4; ++r)
                out[(size_t)(gr + r) * N_TOTAL + go] = acc[mi][r] + bv;
        }
    }

    // ---- epilogue: bounds (reduce over the 16 lanes sharing t>>4) ----
    if (split || m_tile == 0) {
#pragma unroll
        for (int j = 0; j < 4; ++j) {
            float p = P[j], r = R[j];
            p += __shfl_xor(p, 1);
            p += __shfl_xor(p, 2);
            p += __shfl_xor(p, 4);
            p += __shfl_xor(p, 8);
            r += __shfl_xor(r, 1);
            r += __shfl_xor(r, 2);
            r += __shfl_xor(r, 4);
            r += __shfl_xor(r, 8);
            if (sg == 0) {
                int o = n0 + j * 16 + g;
                if (split) {
                    Pp[m_tile * N_TOTAL + o] = p;
                    Rp[m_tile * N_TOTAL + o] = r;
                } else {
                    float bv = bias[o];
                    out[(size_t)M_TOTAL * N_TOTAL + o]           = 0.5f * (p - r) + bv;
                    out[(size_t)M_TOTAL * N_TOTAL + N_TOTAL + o] = 0.5f * (p + r) + bv;
                }
            }
        }
    }
}

// combine K-split bounds partials: low/high = .5*(P -/+ R) + b
__global__ __launch_bounds__(256)
void bounds_combine_kernel(const float* __restrict__ Pp,
                           const float* __restrict__ Rp,
                           const float* __restrict__ bias,
                           float* __restrict__ out) {
    int o = blockIdx.x * 256 + threadIdx.x;   // 0..8191
    float P = 0.f, R = 0.f;
#pragma unroll
    for (int m = 0; m < MT; ++m) {
        P += Pp[m * N_TOTAL + o];
        R += Rp[m * N_TOTAL + o];
    }
    float bv = bias[o];
    out[(size_t)M_TOTAL * N_TOTAL + o]           = 0.5f * (P - R) + bv;
    out[(size_t)M_TOTAL * N_TOTAL + N_TOTAL + o] = 0.5f * (P + R) + bv;
}

extern "C" void kernel_launch(void* const* d_in, const int* in_sizes, int n_in,
                              void* d_out, int out_size, void* d_ws, size_t ws_size,
                              hipStream_t stream) {
    const float* x    = (const float*)d_in[0];
    const float* low  = (const float*)d_in[1];
    const float* high = (const float*)d_in[2];
    const float* W    = (const float*)d_in[3];
    const float* b    = (const float*)d_in[4];
    float* out = (float*)d_out;

    const size_t part_elems = (size_t)MT * N_TOTAL;
    const int split = (ws_size >= 2 * part_elems * sizeof(float)) ? 1 : 0;
    float* Pp = (float*)d_ws;
    float* Rp = Pp + part_elems;

    dim3 grid(MT * (N_TOTAL / TN));   // 1024 blocks
    dim3 block(256);
    hipLaunchKernelGGL(abstract_linear_kernel, grid, block, 0, stream,
                       x, low, high, W, b, out, Pp, Rp, split);
    if (split) {
        hipLaunchKernelGGL(bounds_combine_kernel, dim3(N_TOTAL / 256), dim3(256),
                           0, stream, Pp, Rp, b, out);
    }
}